// Round 1
// baseline (1132.885 us; speedup 1.0000x reference)
//
#include <hip/hip_runtime.h>
#include <stdint.h>

#define NROWS  500000
#define FDIM   132
#define NTILES 7813          // ceil(NROWS/64)
#define PGRID  1536          // persistent grid (3 blocks/CU co-resident, 2 generations)

typedef unsigned short u16;
typedef unsigned int   u32;

typedef __attribute__((ext_vector_type(8))) u16    us8;
typedef __attribute__((ext_vector_type(8))) __bf16 bf16x8;
typedef __attribute__((ext_vector_type(4))) float  f32x4;

__device__ __forceinline__ u16 f2bf(float f) {
    u32 u = __builtin_bit_cast(u32, f);
    u = u + 0x7FFFu + ((u >> 16) & 1u);   // round-to-nearest-even
    return (u16)(u >> 16);
}

// ---------------- pre-kernel: W (f32 [136][136], row=k) -> wt2 bf16 fragment-ordered ----------
// wt2[((kc*9 + t)*64 + lane)*8 + i] = W[k][n], k = kc*32 + (lane>>4)*8 + i, n = t*16 + (lane&15)
// zero for k >= 132 (contr rows handled exactly in f32 tail) or n >= 136 (col padding).
// size: 5*9*64*8 = 23040 u16 = 46080 B
__global__ __launch_bounds__(256) void wconv_kernel(const float* __restrict__ W,
                                                    u16* __restrict__ wt2) {
    int id   = blockIdx.x * 256 + threadIdx.x;   // 23040 ids, grid=90
    int i    = id & 7;
    int lane = (id >> 3) & 63;
    int rest = id >> 9;                          // kc*9 + t, 0..44
    int t = rest % 9, kc = rest / 9;
    int k = kc * 32 + (lane >> 4) * 8 + i;
    int n = t * 16 + (lane & 15);
    float v = (k < 132 && n < 136) ? W[k * 136 + n] : 0.0f;
    wt2[id] = f2bf(v);
}

// ---------------- main kernel: persistent, 64 rows/tile, 256 threads, dbuf A, 3 blocks/CU ----
__global__ __launch_bounds__(256, 3) void exch_kernel(const float* __restrict__ x,
                                                      const float* __restrict__ ev,
                                                      const float* __restrict__ W,
                                                      const float* __restrict__ b,
                                                      const u16* __restrict__ wt2,
                                                      float* __restrict__ out) {
    // LDS: 40960 + 6144 + 4352 + 1024 = 52480 B  -> 3 blocks/CU
    __shared__ __align__(16) u16   A_sh[2][64 * 160];  // bf16 x tile (K padded to 160), swizzled
    __shared__ __align__(16) float ev_sh[64 * 24];     // f32, single buffer (restaged in epiC)
    __shared__ __align__(16) float Wtl_sh[136 * 8];    // [col][0..3]=W[132+d][col], [4]=b[col]
    __shared__ __align__(16) float contr_sh[64 * 4];   // f32 contr; reused as cev after barrier

    const int tid  = threadIdx.x;
    const int lane = tid & 63;
    const int w    = tid >> 6;       // wave 0..3 -> rows [w*16, w*16+16)
    const int ln   = lane & 15;
    const int q    = lane >> 4;

    // ---- once: stage W tail rows (k=132..135) + bias, transposed per-col ----
    if (tid < 136) {
#pragma unroll
        for (int d = 0; d < 4; ++d) Wtl_sh[tid * 8 + d] = W[(132 + d) * 136 + tid];
        Wtl_sh[tid * 8 + 4] = b[tid];
    }

    // staging task split: 4 threads per row, 5 chunks (of 8 cols) each
    const int srow = tid >> 2;       // 0..63
    const int sc0  = tid & 3;

    f32x4 areg[9];   // [2j],[2j+1] = x chunk sc0+4j (j<4); [8] = cols 128..131 (sc0==0 only)
    f32x4 evreg[2];

    // ---- global -> reg loads for tile t64 (zero-filled when OOB) ----
    auto stage_load = [&](int t64) {
        int grow = t64 * 64 + srow;
        bool ok  = grow < NROWS;
        const float* xp = x + (size_t)grow * FDIM;
#pragma unroll
        for (int j = 0; j < 4; ++j) {
            int ch = sc0 + 4 * j;
            f32x4 a0 = {0.f, 0.f, 0.f, 0.f}, a1 = {0.f, 0.f, 0.f, 0.f};
            if (ok) {
                a0 = *(const f32x4*)(xp + ch * 8);
                a1 = *(const f32x4*)(xp + ch * 8 + 4);
            }
            areg[2 * j]     = a0;
            areg[2 * j + 1] = a1;
        }
        f32x4 a2 = {0.f, 0.f, 0.f, 0.f};
        if (ok && sc0 == 0) a2 = *(const f32x4*)(xp + 128);
        areg[8] = a2;
#pragma unroll
        for (int i = 0; i < 2; ++i) {
            int c = tid + i * 256;
            f32x4 e = {0.f, 0.f, 0.f, 0.f};
            if (c < 384) {
                int row = c / 6, j4 = c % 6;
                int g2 = t64 * 64 + row;
                if (g2 < NROWS) e = *(const f32x4*)(ev + (size_t)g2 * 24 + j4 * 4);
            }
            evreg[i] = e;
        }
    };

    // ---- reg -> LDS (cvt bf16, XOR-swizzled); chunks 16..19 land unswizzled ----
    auto stage_write = [&](int buf) {
        u16* base = &A_sh[buf][srow * 160];
#pragma unroll
        for (int j = 0; j < 4; ++j) {
            int ch   = sc0 + 4 * j;
            int phys = ch ^ (srow & 7);
            us8 v;
#pragma unroll
            for (int i = 0; i < 4; ++i) {
                v[i]     = f2bf(areg[2 * j][i]);
                v[i + 4] = f2bf(areg[2 * j + 1][i]);
            }
            *(us8*)(base + phys * 8) = v;
        }
        {
            int ch = 16 + sc0;            // no swizzle on the K-tail chunks
            us8 v;
#pragma unroll
            for (int i = 0; i < 4; ++i) { v[i] = f2bf(areg[8][i]); v[i + 4] = 0; }
            *(us8*)(base + ch * 8) = v;
        }
    };

    auto ev_write = [&]() {
#pragma unroll
        for (int i = 0; i < 2; ++i) {
            int c = tid + i * 256;
            if (c < 384) {
                int row = c / 6, j4 = c % 6;
                *(f32x4*)&ev_sh[row * 24 + j4 * 4] = evreg[i];
            }
        }
    };

    int tile = blockIdx.x;

    // ---- prologue: stage tile0 ----
    stage_load(tile);
    stage_write(0);
    ev_write();
    __syncthreads();

    int buf = 0;
    while (tile < NTILES) {
        int next = tile + PGRID;

        // (1) issue next tile's global loads (latency hides under MFMA + epilogues)
        stage_load(next);

        // (2) contr: 64 rows x 4 segments
        {
            int r = tid >> 2, d = tid & 3;
            int st = d * (d + 2), len = 2 * d + 3;
            float s = 0.f;
            for (int j = 0; j < len; ++j) {
                float v = ev_sh[r * 24 + st + j];
                s += v * v;
            }
            contr_sh[r * 4 + d] = s;
        }

        // (3) MFMA, transposed: acc[t][r] = y[row = w*16+ln][col = t*16 + q*4 + r]
        f32x4 acc[9];
#pragma unroll
        for (int t = 0; t < 9; ++t) acc[t] = (f32x4){0.f, 0.f, 0.f, 0.f};
        {
            const u16* arow = &A_sh[buf][(w * 16 + ln) * 160];
#pragma unroll
            for (int kc = 0; kc < 5; ++kc) {
                int ch   = kc * 4 + q;
                int phys = (kc < 4) ? (ch ^ (ln & 7)) : ch;
                bf16x8 a = __builtin_bit_cast(bf16x8, *(const us8*)(arow + phys * 8));
#pragma unroll
                for (int t = 0; t < 9; ++t) {
                    bf16x8 wf = __builtin_bit_cast(
                        bf16x8, *(const us8*)(wt2 + ((size_t)(kc * 9 + t) * 64 + lane) * 8));
                    acc[t] = __builtin_amdgcn_mfma_f32_16x16x32_bf16(wf, a, acc[t], 0, 0, 0);
                }
            }
        }

        __syncthreads();   // contr visible; A_sh[buf] fully consumed

        // (4.5) write next tile into the other A buffer (loads have had the MFMA phase to land)
        stage_write(buf ^ 1);

        // (5) epilogue A: y += bias + contr * W[132..136)  (exact f32)
        {
            const int row = w * 16 + ln;
            f32x4 cv = *(const f32x4*)&contr_sh[row * 4];
#pragma unroll
            for (int t = 0; t < 9; ++t) {
#pragma unroll
                for (int r = 0; r < 4; ++r) {
                    int col = t * 16 + q * 4 + r;
                    if (col < 136) {
                        f32x4 wl = *(const f32x4*)&Wtl_sh[col * 8];
                        float y  = acc[t][r] + Wtl_sh[col * 8 + 4];
                        y += cv[0] * wl[0] + cv[1] * wl[1] + cv[2] * wl[2] + cv[3] * wl[3];
                        acc[t][r] = y;
                    }
                }
            }
        }

        // (6) epilogue B: float4 cx stores; q==1 stashes cev into contr_sh (own rows only)
        {
            const int row  = w * 16 + ln;
            int       grow = tile * 64 + row;
            bool      ok   = grow < NROWS;
            float*    orow = out + (size_t)grow * FDIM;
#pragma unroll
            for (int t = 0; t < 8; ++t)
                if (ok) *(f32x4*)(orow + t * 16 + q * 4) = acc[t];
            if (q == 0) {
                if (ok) *(f32x4*)(orow + 128) = acc[8];
            } else if (q == 1) {
                *(f32x4*)&contr_sh[row * 4] = acc[8];   // cev
            }
        }

        __syncthreads();   // cev visible to all

        // (8) epilogue C: out1 = cev[seg(m)] * ev ; then restage ev_sh with next tile
#pragma unroll
        for (int i = 0; i < 2; ++i) {
            int c = tid + i * 256;
            if (c < 384) {
                int row  = c / 6, j4 = c % 6;
                int grow = tile * 64 + row;
                if (grow < NROWS) {
                    f32x4 e    = *(const f32x4*)&ev_sh[row * 24 + j4 * 4];
                    f32x4 cev4 = *(const f32x4*)&contr_sh[row * 4];
                    f32x4 o;
#pragma unroll
                    for (int u = 0; u < 4; ++u) {
                        int m = j4 * 4 + u;
                        int d = (m < 3) ? 0 : (m < 8) ? 1 : (m < 15) ? 2 : 3;
                        o[u] = cev4[d] * e[u];
                    }
                    *(f32x4*)(out + (size_t)NROWS * FDIM + (size_t)grow * 24 + j4 * 4) = o;
                }
                *(f32x4*)&ev_sh[row * 24 + j4 * 4] = evreg[i];   // same thread owns this slot
            }
        }

        __syncthreads();   // ev/A stage writes visible for next iteration
        tile = next;
        buf ^= 1;
    }
}

extern "C" void kernel_launch(void* const* d_in, const int* in_sizes, int n_in,
                              void* d_out, int out_size, void* d_ws, size_t ws_size,
                              hipStream_t stream) {
    const float* x  = (const float*)d_in[0];
    const float* ev = (const float*)d_in[1];
    const float* W  = (const float*)d_in[2];
    const float* b  = (const float*)d_in[3];
    u16* wt2 = (u16*)d_ws;   // needs 46080 B

    wconv_kernel<<<90, 256, 0, stream>>>(W, wt2);
    exch_kernel<<<PGRID, 256, 0, stream>>>(x, ev, W, b, wt2, (float*)d_out);
}